// Round 12
// baseline (176.241 us; speedup 1.0000x reference)
//
#include <hip/hip_runtime.h>
#include <hip/hip_bf16.h>
#include <math.h>

#define NTOK 131072
#define DIM  256
#define EDIM 512
#define NB   16
#define NL   64
#define NSEG (NB*NL)    // 1024
#define K3D  768        // 3*DIM
#define K2D  512        // 2*DIM
#define HB   64         // histogram/scatter blocks (2048 tokens each)
#define K4CH 256        // k4 LDS staging chunk (tokens)

typedef __attribute__((ext_vector_type(8))) short short8;
typedef __attribute__((ext_vector_type(4))) float f32x4;

// monotone float<->uint code so atomicMax(uint) == float max
static __device__ __forceinline__ unsigned fcode(float x){
  unsigned b = __float_as_uint(x);
  return (b & 0x80000000u) ? ~b : (b | 0x80000000u);
}
static __device__ __forceinline__ float fdecode(unsigned c){
  unsigned b = (c & 0x80000000u) ? (c ^ 0x80000000u) : ~c;
  return __uint_as_float(b);
}
#define NEG_INF_CODE 0x007FFFFFu   // fcode(-inf)

static __device__ __forceinline__ short f2bf(float x){
  union { __hip_bfloat16 h; short s; } u; u.h = __float2bfloat16(x); return u.s;
}
static __device__ __forceinline__ float bf2f(short s){
  union { float f; unsigned u; } u; u.u = ((unsigned)(unsigned short)s) << 16; return u.f;
}

// ---------------- K0t: transpose+convert weights to bf16 [N][K]; init bmax + segcnt ----------------
__global__ __launch_bounds__(256) void k0_transpose(const float* __restrict__ W1, const float* __restrict__ W2,
                                                    const float* __restrict__ Wc,
                                                    short* __restrict__ W1t, short* __restrict__ W2t,
                                                    short* __restrict__ Wct, unsigned* __restrict__ bmax,
                                                    int* __restrict__ segcnt){
  if (blockIdx.x == 0){
    if (threadIdx.x < NB) bmax[threadIdx.x] = NEG_INF_CODE;
    for (int i = threadIdx.x; i < NSEG; i += 256) segcnt[i] = 0;
  }
  __shared__ short tile[64][65];
  int b = blockIdx.x;
  const float* src; short* dst; int K, N, kt, nt;
  if (b < 96){ src=W1; dst=W1t; K=768; N=512; kt=b/8;  nt=b%8;  }
  else if (b < 128){ int c=b-96;  src=W2; dst=W2t; K=512; N=256; kt=c/4; nt=c%4; }
  else             { int c=b-128; src=Wc; dst=Wct; K=512; N=256; kt=c/4; nt=c%4; }
  int k0 = kt*64, n0 = nt*64;
  for (int e = threadIdx.x; e < 4096; e += 256){
    int r = e >> 6, c = e & 63;                       // r: k-row, c: n-col (coalesced read)
    tile[c][r] = f2bf(src[(size_t)(k0+r)*N + n0 + c]);
  }
  __syncthreads();
  for (int e = threadIdx.x; e < 4096; e += 256){
    int r = e >> 6, c = e & 63;                       // r: n-row, c: k-col (coalesced write)
    dst[(size_t)(n0+r)*K + k0 + c] = tile[r][c];
  }
}

// ---------------- K1 v6: logits + seg + per-batch max + bf16 emit, phase-split ----------------
// Phase A: pure memory (16 contiguous-256B loads, dots, featsb stores) — no cross-lane ops
// anywhere in the load path. Phase B: shfl reduces + lane-0 scalar outputs.
template<int WRITEB>
__global__ __launch_bounds__(256) void k1_logits(const float* __restrict__ feats, const int* __restrict__ cu,
    const int* __restrict__ layer_ids, const float* __restrict__ Wa, const float* __restrict__ ba,
    float* __restrict__ logits, int* __restrict__ seg, unsigned* __restrict__ bmax,
    short* __restrict__ featsb){
  __shared__ int      lcu[NB];
  __shared__ unsigned lbm[NB];
  int tid = threadIdx.x;
  if (tid < NB){ lcu[tid] = cu[tid+1]; lbm[tid] = NEG_INF_CODE; }
  int s = tid & 15;                      // lane within row
  int rowoff = tid >> 4;                 // 0..15
  float4 w0 = *(const float4*)(Wa + s*4);
  float4 w1 = *(const float4*)(Wa + 64 + s*4);
  float4 w2 = *(const float4*)(Wa + 128 + s*4);
  float4 w3 = *(const float4*)(Wa + 192 + s*4);
  float bav = ba[0];
  __syncthreads();
  float a[4];
#pragma unroll
  for (int it = 0; it < 4; ++it){
    int r = (blockIdx.x + it*2048)*16 + rowoff;
    const float4* fp = (const float4*)(feats + (size_t)r*DIM);
    float4 x0 = fp[s], x1 = fp[16+s], x2 = fp[32+s], x3 = fp[48+s];
    a[it] = x0.x*w0.x + x0.y*w0.y + x0.z*w0.z + x0.w*w0.w
          + x1.x*w1.x + x1.y*w1.y + x1.z*w1.z + x1.w*w1.w
          + x2.x*w2.x + x2.y*w2.y + x2.z*w2.z + x2.w*w2.w
          + x3.x*w3.x + x3.y*w3.y + x3.z*w3.z + x3.w*w3.w;
    if (WRITEB){
      short4* ob = (short4*)(featsb + (size_t)r*DIM);
      short4 v;
      v.x=f2bf(x0.x); v.y=f2bf(x0.y); v.z=f2bf(x0.z); v.w=f2bf(x0.w); ob[s]    = v;
      v.x=f2bf(x1.x); v.y=f2bf(x1.y); v.z=f2bf(x1.z); v.w=f2bf(x1.w); ob[16+s] = v;
      v.x=f2bf(x2.x); v.y=f2bf(x2.y); v.z=f2bf(x2.z); v.w=f2bf(x2.w); ob[32+s] = v;
      v.x=f2bf(x3.x); v.y=f2bf(x3.y); v.z=f2bf(x3.z); v.w=f2bf(x3.w); ob[48+s] = v;
    }
  }
#pragma unroll
  for (int it = 0; it < 4; ++it){
    float v = a[it];
    v += __shfl_xor(v, 1);
    v += __shfl_xor(v, 2);
    v += __shfl_xor(v, 4);
    v += __shfl_xor(v, 8);
    if (s == 0){
      int r = (blockIdx.x + it*2048)*16 + rowoff;
      float lg = v + bav;
      logits[r] = lg;
      int b = 0;
#pragma unroll
      for (int j = 0; j < NB-1; ++j) b += (lcu[j] <= r) ? 1 : 0;
      seg[r] = b*NL + layer_ids[r];
      atomicMax(&lbm[b], fcode(lg));
    }
  }
  __syncthreads();
  if (tid < NB && lbm[tid] != NEG_INF_CODE) atomicMax(&bmax[tid], lbm[tid]);
}

// ---------------- K23: fused {segment counts | batch-Z} ----------------
__global__ __launch_bounds__(256) void k23_hist_z(const int* __restrict__ seg, int* __restrict__ segcnt,
    const float* __restrict__ logits, const int* __restrict__ cu,
    const unsigned* __restrict__ bmax, float* __restrict__ bz){
  __shared__ int h[NSEG];
  int bid = blockIdx.x;
  if (bid < HB){
    for (int i = threadIdx.x; i < NSEG; i += 256) h[i] = 0;
    __syncthreads();
    int base = bid * (NTOK/HB);
    for (int i = threadIdx.x; i < NTOK/HB; i += 256) atomicAdd(&h[seg[base+i]], 1);
    __syncthreads();
    for (int i = threadIdx.x; i < NSEG; i += 256){ int c = h[i]; if (c) atomicAdd(&segcnt[i], c); }
  } else {
    float* red = (float*)h;
    int b = bid - HB;
    int s = cu[b], e = cu[b+1];
    float m = fdecode(bmax[b]);
    float acc = 0.f;
    for (int i = s + threadIdx.x; i < e; i += 256)
      acc += expf(logits[i] - m);
    red[threadIdx.x] = acc; __syncthreads();
    for (int off = 128; off; off >>= 1){
      if (threadIdx.x < off) red[threadIdx.x] += red[threadIdx.x + off];
      __syncthreads();
    }
    if (threadIdx.x == 0) bz[b] = red[0];
  }
}

// ---------------- K3b: scan segcnt -> segstart + cur (single tiny block) ----------------
__global__ __launch_bounds__(1024) void k3b_scan(const int* __restrict__ segcnt, int* __restrict__ segstart,
                                                 int* __restrict__ cur){
  __shared__ int sc[NSEG];
  int s = threadIdx.x;
  int tot = segcnt[s];
  sc[s] = tot; __syncthreads();
  for (int off = 1; off < NSEG; off <<= 1){
    int v = (s >= off) ? sc[s-off] : 0;
    __syncthreads();
    sc[s] += v;
    __syncthreads();
  }
  int base = sc[s] - tot;   // exclusive prefix
  segstart[s] = base;
  cur[s] = base;
  if (s == 0) segstart[NSEG] = NTOK;
}

// ---------------- K3c: scatter via per-seg global range reservation ----------------
__global__ __launch_bounds__(256) void k3c_scatter(const int* __restrict__ seg, int* __restrict__ cur,
                                                   int* __restrict__ sorted){
  __shared__ int h[NSEG];
  for (int i = threadIdx.x; i < NSEG; i += 256) h[i] = 0;
  __syncthreads();
  int base = blockIdx.x * (NTOK/HB);
  for (int i = threadIdx.x; i < NTOK/HB; i += 256) atomicAdd(&h[seg[base+i]], 1);
  __syncthreads();
  for (int i = threadIdx.x; i < NSEG; i += 256){
    int c = h[i];
    if (c) h[i] = atomicAdd(&cur[i], c);     // reserve contiguous range; h becomes cursor
  }
  __syncthreads();
  for (int i = threadIdx.x; i < NTOK/HB; i += 256){
    int sg = seg[base+i];
    int p = atomicAdd(&h[sg], 1);
    sorted[p] = base+i;
  }
}

// ---------------- K4: segmented reduce over sorted tokens -> pooled [1024][768] bf16 ----------------
template<int USEB>
__global__ __launch_bounds__(256) void k4_pool(const float* __restrict__ feats, const short* __restrict__ featsb,
    const int* __restrict__ sorted, const int* __restrict__ segstart,
    const float* __restrict__ logits, const unsigned* __restrict__ bmax, const float* __restrict__ bz,
    short* __restrict__ pooledb){
  __shared__ float redS[4][DIM];
  __shared__ float redM[4][DIM];
  __shared__ float redA[4][DIM];
  __shared__ int   ltok[K4CH];
  __shared__ float lwgt[K4CH];
  int sgi = blockIdx.x;
  int b = sgi >> 6;
  int s = segstart[sgi], e = segstart[sgi+1];
  int cnt = e - s;
  float m = fdecode(bmax[b]);
  float invz = 1.0f / bz[b];
  int lane = threadIdx.x & 63, grp = threadIdx.x >> 6;
  float4 sum = make_float4(0.f,0.f,0.f,0.f), att = make_float4(0.f,0.f,0.f,0.f);
  float4 mx  = make_float4(-INFINITY,-INFINITY,-INFINITY,-INFINITY);
  for (int c0 = s; c0 < e; c0 += K4CH){
    int csz = min(K4CH, e - c0);
    for (int j = threadIdx.x; j < csz; j += 256){
      int t = sorted[c0 + j];
      ltok[j] = t;
      lwgt[j] = expf(logits[t] - m) * invz;
    }
    __syncthreads();
    for (int j = grp; j < csz; j += 4){
      int tok = ltok[j];
      float w = lwgt[j];
      float4 x;
      if (USEB){
        short4 h = *(const short4*)(featsb + (size_t)tok*DIM + lane*4);
        x = make_float4(bf2f(h.x), bf2f(h.y), bf2f(h.z), bf2f(h.w));
      } else {
        x = *(const float4*)(feats + (size_t)tok*DIM + lane*4);
      }
      sum.x += x.x; sum.y += x.y; sum.z += x.z; sum.w += x.w;
      mx.x = fmaxf(mx.x, x.x); mx.y = fmaxf(mx.y, x.y);
      mx.z = fmaxf(mx.z, x.z); mx.w = fmaxf(mx.w, x.w);
      att.x += x.x*w; att.y += x.y*w; att.z += x.z*w; att.w += x.w*w;
    }
    __syncthreads();
  }
  *(float4*)&redS[grp][lane*4] = sum;
  *(float4*)&redM[grp][lane*4] = mx;
  *(float4*)&redA[grp][lane*4] = att;
  __syncthreads();
  int d = threadIdx.x;
  float rs = redS[0][d] + redS[1][d] + redS[2][d] + redS[3][d];
  float rm = fmaxf(fmaxf(redM[0][d], redM[1][d]), fmaxf(redM[2][d], redM[3][d]));
  float ra = redA[0][d] + redA[1][d] + redA[2][d] + redA[3][d];
  float inv = 1.0f / (float)(cnt > 1 ? cnt : 1);
  size_t rb_ = (size_t)sgi * K3D;
  pooledb[rb_ + d]         = f2bf(rs * inv);
  pooledb[rb_ + DIM + d]   = f2bf(cnt > 0 ? rm : 0.f);
  pooledb[rb_ + 2*DIM + d] = f2bf(ra);
}

// ---------------- K_mlp: fused MLP chain per 16-row panel ----------------
// h = gelu(pooled @ W1 + b1); lfb = h @ W2 + b2; lfp = lfb @ Wc[0:256] + bc.
// Panels live in LDS; B-operands read direct from L2-resident bf16 weights.
// grid 64 x 256 threads (4 waves; wave = col-slice).
__global__ __launch_bounds__(256) void k_mlp(const short* __restrict__ pooledb,
    const short* __restrict__ W1t, const float* __restrict__ b1,
    const short* __restrict__ W2t, const float* __restrict__ b2,
    const short* __restrict__ Wct, const float* __restrict__ bc,
    float* __restrict__ lfp){
  __shared__ short lA[16][776];   // pooled panel (768 + 8 pad)
  __shared__ short lh[16][520];   // h panel (512 + 8 pad)
  __shared__ short lf[16][264];   // lfb panel (256 + 8 pad)
  int tid = threadIdx.x;
  int wave = tid >> 6, lane = tid & 63;
  int l15 = lane & 15, lg = lane >> 4;
  int r0 = blockIdx.x * 16;
  for (int i = tid; i < 16*96; i += 256){
    int row = i / 96, c8 = i % 96;
    *(short8*)&lA[row][c8*8] = *(const short8*)(pooledb + (size_t)(r0+row)*K3D + c8*8);
  }
  __syncthreads();
  { // step 1: 512 cols, wave owns 128
    f32x4 acc[8] = {};
    int wc = wave * 128;
    for (int ks = 0; ks < K3D; ks += 32){
      short8 af = *(const short8*)&lA[l15][ks + lg*8];
#pragma unroll
      for (int fn = 0; fn < 8; ++fn){
        short8 bf = *(const short8*)(W1t + (size_t)(wc + fn*16 + l15)*K3D + ks + lg*8);
        acc[fn] = __builtin_amdgcn_mfma_f32_16x16x32_bf16(af, bf, acc[fn], 0, 0, 0);
      }
    }
#pragma unroll
    for (int fn = 0; fn < 8; ++fn){
      int col = wc + fn*16 + l15;
      float bcv = b1[col];
#pragma unroll
      for (int r = 0; r < 4; ++r){
        float v = acc[fn][r] + bcv;
        v = 0.5f * v * (1.0f + erff(v * 0.70710678118f));
        lh[lg*4 + r][col] = f2bf(v);
      }
    }
  }
  __syncthreads();
  { // step 2: 256 cols, wave owns 64
    f32x4 acc[4] = {};
    int wc = wave * 64;
    for (int ks = 0; ks < EDIM; ks += 32){
      short8 af = *(const short8*)&lh[l15][ks + lg*8];
#pragma unroll
      for (int fn = 0; fn < 4; ++fn){
        short8 bf = *(const short8*)(W2t + (size_t)(wc + fn*16 + l15)*EDIM + ks + lg*8);
        acc[fn] = __builtin_amdgcn_mfma_f32_16x16x32_bf16(af, bf, acc[fn], 0, 0, 0);
      }
    }
#pragma unroll
    for (int fn = 0; fn < 4; ++fn){
      int col = wc + fn*16 + l15;
      float bcv = b2[col];
#pragma unroll
      for (int r = 0; r < 4; ++r)
        lf[lg*4 + r][col] = f2bf(acc[fn][r] + bcv);
    }
  }
  __syncthreads();
  { // step 3: 256 cols, wave owns 64, K=256 (gathered half of Wc)
    f32x4 acc[4] = {};
    int wc = wave * 64;
    for (int ks = 0; ks < 256; ks += 32){
      short8 af = *(const short8*)&lf[l15][ks + lg*8];
#pragma unroll
      for (int fn = 0; fn < 4; ++fn){
        short8 bf = *(const short8*)(Wct + (size_t)(wc + fn*16 + l15)*K2D + ks + lg*8);
        acc[fn] = __builtin_amdgcn_mfma_f32_16x16x32_bf16(af, bf, acc[fn], 0, 0, 0);
      }
    }
#pragma unroll
    for (int fn = 0; fn < 4; ++fn){
      int col = wc + fn*16 + l15;
      float bcv = bc[col];
#pragma unroll
      for (int r = 0; r < 4; ++r)
        lfp[(size_t)(r0 + lg*4 + r)*DIM + col] = acc[fn][r] + bcv;
    }
  }
}

// ---------------- K5 v4: out = featsb @ Wct[:,256:512]^T + gather(lfp, seg) ----------------
template<int USEB>
__global__ __launch_bounds__(512, 4) void k5_final(const float* __restrict__ feats,
    const short* __restrict__ featsb, const float* __restrict__ lfp,
    const int* __restrict__ seg, const short* __restrict__ Wct,
    float* __restrict__ out){
  __shared__ short lA[2][128][72];
  __shared__ short lB[2][128][72];
  int tid = threadIdx.x;
  int wave = tid >> 6, lane = tid & 63;
  int wm = wave >> 2, wn = wave & 3;
  int bid = (int)blockIdx.x;
  int swz = (bid & 7) * 256 + (bid >> 3);     // XCD-aware, bijective (2048 % 8 == 0)
  int rb = (swz >> 1) * 128;                  // adjacent swz share the A row-panel
  int cb = (swz & 1) * 128;
  int l15 = lane & 15, lg = lane >> 4;
  int arow0 = tid >> 3, arow1 = (tid >> 3) + 64, akg = tid & 7;
  const short* fbp0  = featsb + (size_t)(rb + arow0)*DIM + akg*8;
  const short* fbp1  = featsb + (size_t)(rb + arow1)*DIM + akg*8;
  const float* ffp0  = feats  + (size_t)(rb + arow0)*DIM + akg*8;
  const float* ffp1  = feats  + (size_t)(rb + arow1)*DIM + akg*8;
  const short* wp0 = Wct + (size_t)(cb + arow0)*K2D + 256 + akg*8;   // feats half of Wc
  const short* wp1 = Wct + (size_t)(cb + arow1)*K2D + 256 + akg*8;
  short8 ra0, ra1, rb0, rb1; float4 fa00, fa01, fa10, fa11;
  auto LOAD = [&](int t){
    if (USEB){
      ra0 = *(const short8*)(fbp0 + t*64);
      ra1 = *(const short8*)(fbp1 + t*64);
    } else {
      const float* p0 = ffp0 + (size_t)t*64; fa00 = *(const float4*)p0; fa01 = *(const float4*)(p0+4);
      const float* p1 = ffp1 + (size_t)t*64; fa10 = *(const float4*)p1; fa11 = *(const float4*)(p1+4);
    }
    rb0 = *(const short8*)(wp0 + t*64);
    rb1 = *(const short8*)(wp1 + t*64);
  };
  auto WRITE = [&](int t){
    int buf = t & 1;
    if (!USEB){
      short8 v;
      v[0]=f2bf(fa00.x); v[1]=f2bf(fa00.y); v[2]=f2bf(fa00.z); v[3]=f2bf(fa00.w);
      v[4]=f2bf(fa01.x); v[5]=f2bf(fa01.y); v[6]=f2bf(fa01.z); v[7]=f2bf(fa01.w);
      *(short8*)&lA[buf][arow0][akg*8] = v;
      v[0]=f2bf(fa10.x); v[1]=f2bf(fa10.y); v[2]=f2bf(fa10.z); v[3]=f2bf(fa10.w);
      v[4]=f2bf(fa11.x); v[5]=f2bf(fa11.y); v[6]=f2bf(fa11.z); v[7]=f2bf(fa11.w);
      *(short8*)&lA[buf][arow1][akg*8] = v;
    } else {
      *(short8*)&lA[buf][arow0][akg*8] = ra0;
      *(short8*)&lA[buf][arow1][akg*8] = ra1;
    }
    *(short8*)&lB[buf][arow0][akg*8] = rb0;
    *(short8*)&lB[buf][arow1][akg*8] = rb1;
  };
  f32x4 acc[4][2] = {};
  LOAD(0); WRITE(0); LOAD(1);
  __syncthreads();
  for (int ks = 0; ks < 4; ++ks){
    int cur = ks & 1;
    if (ks < 3) WRITE(ks+1);
    if (ks < 2) LOAD(ks+2);
#pragma unroll
    for (int kk = 0; kk < 2; ++kk){
      short8 af[4], bf[2];
#pragma unroll
      for (int f = 0; f < 4; ++f)
        af[f] = *(const short8*)&lA[cur][wm*64 + f*16 + l15][kk*32 + lg*8];
#pragma unroll
      for (int f = 0; f < 2; ++f)
        bf[f] = *(const short8*)&lB[cur][wn*32 + f*16 + l15][kk*32 + lg*8];
#pragma unroll
      for (int fm = 0; fm < 4; ++fm)
#pragma unroll
        for (int fn = 0; fn < 2; ++fn)
          acc[fm][fn] = __builtin_amdgcn_mfma_f32_16x16x32_bf16(af[fm], bf[fn], acc[fm][fn], 0, 0, 0);
    }
    __syncthreads();
  }
#pragma unroll
  for (int fm = 0; fm < 4; ++fm){
    int rbase = rb + wm*64 + fm*16 + lg*4;
    int4 sg4 = *(const int4*)(seg + rbase);
    int sgs[4] = {sg4.x, sg4.y, sg4.z, sg4.w};
#pragma unroll
    for (int fn = 0; fn < 2; ++fn){
      int col = cb + wn*32 + fn*16 + l15;
#pragma unroll
      for (int r = 0; r < 4; ++r){
        out[(size_t)(rbase+r)*DIM + col] = acc[fm][fn][r] + lfp[(size_t)sgs[r]*DIM + col];
      }
    }
  }
}

extern "C" void kernel_launch(void* const* d_in, const int* in_sizes, int n_in,
                              void* d_out, int out_size, void* d_ws, size_t ws_size,
                              hipStream_t stream){
  const float* feats     = (const float*)d_in[0];
  const int*   cu        = (const int*)d_in[1];
  const int*   layer_ids = (const int*)d_in[2];
  const float* Wa        = (const float*)d_in[3];
  const float* ba        = (const float*)d_in[4];
  const float* W1        = (const float*)d_in[5];
  const float* b1        = (const float*)d_in[6];
  const float* W2        = (const float*)d_in[7];
  const float* b2        = (const float*)d_in[8];
  const float* Wc        = (const float*)d_in[9];
  const float* bc        = (const float*)d_in[10];
  float* out = (float*)d_out;

  char* w = (char*)d_ws;
  auto alloc = [&](size_t bytes)->char*{ char* p = w; w += (bytes + 255) & ~255ull; return p; };
  float*    logits  = (float*)   alloc((size_t)NTOK*4);
  int*      seg     = (int*)     alloc((size_t)NTOK*4);
  int*      sorted  = (int*)     alloc((size_t)NTOK*4);
  int*      segcnt  = (int*)     alloc((size_t)NSEG*4);
  int*      segstart= (int*)     alloc((size_t)(NSEG+1)*4);
  int*      cur     = (int*)     alloc((size_t)NSEG*4);
  unsigned* bmax    = (unsigned*)alloc(NB*4);
  float*    bz      = (float*)   alloc(NB*4);
  short*    W1t     = (short*)   alloc((size_t)512*768*2);
  short*    W2t     = (short*)   alloc((size_t)256*512*2);
  short*    Wct     = (short*)   alloc((size_t)256*512*2);
  short*    pooledb = (short*)   alloc((size_t)NSEG*K3D*2);
  float*    lfp     = (float*)   alloc((size_t)NSEG*DIM*4);
  short*    featsb  = (short*)   alloc((size_t)NTOK*DIM*2);     // 67 MB, gated
  size_t need = (size_t)(w - (char*)d_ws);
  bool useb = (ws_size >= need);

  k0_transpose<<<dim3(160), dim3(256), 0, stream>>>(W1, W2, Wc, W1t, W2t, Wct, bmax, segcnt);
  if (useb)
    k1_logits<1><<<dim3(2048), dim3(256), 0, stream>>>(feats, cu, layer_ids, Wa, ba, logits, seg, bmax, featsb);
  else
    k1_logits<0><<<dim3(2048), dim3(256), 0, stream>>>(feats, cu, layer_ids, Wa, ba, logits, seg, bmax, featsb);
  k23_hist_z<<<dim3(HB + NB), dim3(256), 0, stream>>>(seg, segcnt, logits, cu, bmax, bz);
  k3b_scan<<<dim3(1), dim3(1024), 0, stream>>>(segcnt, segstart, cur);
  k3c_scatter<<<dim3(HB), dim3(256), 0, stream>>>(seg, cur, sorted);
  if (useb)
    k4_pool<1><<<dim3(NSEG), dim3(256), 0, stream>>>(feats, featsb, sorted, segstart, logits, bmax, bz, pooledb);
  else
    k4_pool<0><<<dim3(NSEG), dim3(256), 0, stream>>>(feats, featsb, sorted, segstart, logits, bmax, bz, pooledb);
  k_mlp<<<dim3(64), dim3(256), 0, stream>>>(pooledb, W1t, b1, W2t, b2, Wct, bc, lfp);
  if (useb)
    k5_final<1><<<dim3(2048), dim3(512), 0, stream>>>(feats, featsb, lfp, seg, Wct, out);
  else
    k5_final<0><<<dim3(2048), dim3(512), 0, stream>>>(feats, featsb, lfp, seg, Wct, out);
}

// Round 14
// 161.161 us; speedup vs baseline: 1.0936x; 1.0936x over previous
//
#include <hip/hip_runtime.h>
#include <hip/hip_bf16.h>
#include <math.h>

#define NTOK 131072
#define DIM  256
#define EDIM 512
#define NB   16
#define NL   64
#define NSEG (NB*NL)    // 1024
#define K3D  768        // 3*DIM
#define K2D  512        // 2*DIM
#define HB   64         // histogram/scatter blocks (2048 tokens each)
#define K4CH 256        // k4 LDS staging chunk (tokens)

typedef __attribute__((ext_vector_type(8))) short short8;
typedef __attribute__((ext_vector_type(4))) float f32x4;

// monotone float<->uint code so atomicMax(uint) == float max
static __device__ __forceinline__ unsigned fcode(float x){
  unsigned b = __float_as_uint(x);
  return (b & 0x80000000u) ? ~b : (b | 0x80000000u);
}
static __device__ __forceinline__ float fdecode(unsigned c){
  unsigned b = (c & 0x80000000u) ? (c ^ 0x80000000u) : ~c;
  return __uint_as_float(b);
}
#define NEG_INF_CODE 0x007FFFFFu   // fcode(-inf)

static __device__ __forceinline__ short f2bf(float x){
  union { __hip_bfloat16 h; short s; } u; u.h = __float2bfloat16(x); return u.s;
}
static __device__ __forceinline__ float bf2f(short s){
  union { float f; unsigned u; } u; u.u = ((unsigned)(unsigned short)s) << 16; return u.f;
}

// ---------------- K0t: transpose+convert weights to bf16 [N][K]; init bmax + segcnt ----------------
__global__ __launch_bounds__(256) void k0_transpose(const float* __restrict__ W1, const float* __restrict__ W2,
                                                    const float* __restrict__ Wc,
                                                    short* __restrict__ W1t, short* __restrict__ W2t,
                                                    short* __restrict__ Wct, unsigned* __restrict__ bmax,
                                                    int* __restrict__ segcnt){
  if (blockIdx.x == 0){
    if (threadIdx.x < NB) bmax[threadIdx.x] = NEG_INF_CODE;
    for (int i = threadIdx.x; i < NSEG; i += 256) segcnt[i] = 0;
  }
  __shared__ short tile[64][65];
  int b = blockIdx.x;
  const float* src; short* dst; int K, N, kt, nt;
  if (b < 96){ src=W1; dst=W1t; K=768; N=512; kt=b/8;  nt=b%8;  }
  else if (b < 128){ int c=b-96;  src=W2; dst=W2t; K=512; N=256; kt=c/4; nt=c%4; }
  else             { int c=b-128; src=Wc; dst=Wct; K=512; N=256; kt=c/4; nt=c%4; }
  int k0 = kt*64, n0 = nt*64;
  for (int e = threadIdx.x; e < 4096; e += 256){
    int r = e >> 6, c = e & 63;                       // r: k-row, c: n-col (coalesced read)
    tile[c][r] = f2bf(src[(size_t)(k0+r)*N + n0 + c]);
  }
  __syncthreads();
  for (int e = threadIdx.x; e < 4096; e += 256){
    int r = e >> 6, c = e & 63;                       // r: n-row, c: k-col (coalesced write)
    dst[(size_t)(n0+r)*K + k0 + c] = tile[r][c];
  }
}

// ---------------- K1 v5+: logits + seg + per-batch max + bf16 emit + segcnt hist ----------------
// 16 lanes per row (contiguous 256B per load instruction) x 64 rows per block. Wa in regs.
// feats loads nontemporal in WRITEB path (read-once; keep L3 for featsb). Per-block LDS
// segment hist flushed with <=64 global atomics (removes the separate hist pass).
template<int WRITEB>
__global__ __launch_bounds__(256) void k1_logits(const float* __restrict__ feats, const int* __restrict__ cu,
    const int* __restrict__ layer_ids, const float* __restrict__ Wa, const float* __restrict__ ba,
    float* __restrict__ logits, int* __restrict__ seg, unsigned* __restrict__ bmax,
    short* __restrict__ featsb, int* __restrict__ segcnt){
  __shared__ int      lcu[NB];
  __shared__ unsigned lbm[NB];
  __shared__ int      h[NSEG];
  int tid = threadIdx.x;
  if (tid < NB){ lcu[tid] = cu[tid+1]; lbm[tid] = NEG_INF_CODE; }
  for (int i = tid; i < NSEG; i += 256) h[i] = 0;
  int s = tid & 15;                      // lane within row
  int rowoff = tid >> 4;                 // 0..15
  f32x4 w0 = *(const f32x4*)(Wa + s*4);
  f32x4 w1 = *(const f32x4*)(Wa + 64 + s*4);
  f32x4 w2 = *(const f32x4*)(Wa + 128 + s*4);
  f32x4 w3 = *(const f32x4*)(Wa + 192 + s*4);
  float bav = ba[0];
  __syncthreads();
#pragma unroll
  for (int it = 0; it < 4; ++it){
    int r = (blockIdx.x + it*2048)*16 + rowoff;
    const f32x4* fp = (const f32x4*)(feats + (size_t)r*DIM);
    f32x4 x0, x1, x2, x3;
    if (WRITEB){
      x0 = __builtin_nontemporal_load(fp + s);
      x1 = __builtin_nontemporal_load(fp + 16 + s);
      x2 = __builtin_nontemporal_load(fp + 32 + s);
      x3 = __builtin_nontemporal_load(fp + 48 + s);
    } else {
      x0 = fp[s]; x1 = fp[16+s]; x2 = fp[32+s]; x3 = fp[48+s];
    }
    float a = x0[0]*w0[0] + x0[1]*w0[1] + x0[2]*w0[2] + x0[3]*w0[3]
            + x1[0]*w1[0] + x1[1]*w1[1] + x1[2]*w1[2] + x1[3]*w1[3]
            + x2[0]*w2[0] + x2[1]*w2[1] + x2[2]*w2[2] + x2[3]*w2[3]
            + x3[0]*w3[0] + x3[1]*w3[1] + x3[2]*w3[2] + x3[3]*w3[3];
    if (WRITEB){
      short4* ob = (short4*)(featsb + (size_t)r*DIM);
      short4 v;
      v.x=f2bf(x0[0]); v.y=f2bf(x0[1]); v.z=f2bf(x0[2]); v.w=f2bf(x0[3]); ob[s]    = v;
      v.x=f2bf(x1[0]); v.y=f2bf(x1[1]); v.z=f2bf(x1[2]); v.w=f2bf(x1[3]); ob[16+s] = v;
      v.x=f2bf(x2[0]); v.y=f2bf(x2[1]); v.z=f2bf(x2[2]); v.w=f2bf(x2[3]); ob[32+s] = v;
      v.x=f2bf(x3[0]); v.y=f2bf(x3[1]); v.z=f2bf(x3[2]); v.w=f2bf(x3[3]); ob[48+s] = v;
    }
    a += __shfl_xor(a, 1);
    a += __shfl_xor(a, 2);
    a += __shfl_xor(a, 4);
    a += __shfl_xor(a, 8);
    if (s == 0){
      float lg = a + bav;
      logits[r] = lg;
      int b = 0;
#pragma unroll
      for (int j = 0; j < NB-1; ++j) b += (lcu[j] <= r) ? 1 : 0;
      int sg = b*NL + layer_ids[r];
      seg[r] = sg;
      atomicAdd(&h[sg], 1);
      atomicMax(&lbm[b], fcode(lg));
    }
  }
  __syncthreads();
  if (tid < NB && lbm[tid] != NEG_INF_CODE) atomicMax(&bmax[tid], lbm[tid]);
  for (int i = tid; i < NSEG; i += 256){ int c = h[i]; if (c) atomicAdd(&segcnt[i], c); }
}

// ---------------- K2z: per-batch softmax denominator (16 blocks) ----------------
__global__ __launch_bounds__(256) void k2_z(const float* __restrict__ logits, const int* __restrict__ cu,
    const unsigned* __restrict__ bmax, float* __restrict__ bz){
  __shared__ float red[256];
  int b = blockIdx.x;
  int s = cu[b], e = cu[b+1];
  float m = fdecode(bmax[b]);
  float acc = 0.f;
  for (int i = s + threadIdx.x; i < e; i += 256)
    acc += expf(logits[i] - m);
  red[threadIdx.x] = acc; __syncthreads();
  for (int off = 128; off; off >>= 1){
    if (threadIdx.x < off) red[threadIdx.x] += red[threadIdx.x + off];
    __syncthreads();
  }
  if (threadIdx.x == 0) bz[b] = red[0];
}

// ---------------- K3b: scan segcnt -> segstart + cur (single tiny block) ----------------
__global__ __launch_bounds__(1024) void k3b_scan(const int* __restrict__ segcnt, int* __restrict__ segstart,
                                                 int* __restrict__ cur){
  __shared__ int sc[NSEG];
  int s = threadIdx.x;
  int tot = segcnt[s];
  sc[s] = tot; __syncthreads();
  for (int off = 1; off < NSEG; off <<= 1){
    int v = (s >= off) ? sc[s-off] : 0;
    __syncthreads();
    sc[s] += v;
    __syncthreads();
  }
  int base = sc[s] - tot;   // exclusive prefix
  segstart[s] = base;
  cur[s] = base;
  if (s == 0) segstart[NSEG] = NTOK;
}

// ---------------- K3c: scatter via per-seg global range reservation ----------------
__global__ __launch_bounds__(256) void k3c_scatter(const int* __restrict__ seg, int* __restrict__ cur,
                                                   int* __restrict__ sorted){
  __shared__ int h[NSEG];
  for (int i = threadIdx.x; i < NSEG; i += 256) h[i] = 0;
  __syncthreads();
  int base = blockIdx.x * (NTOK/HB);
  for (int i = threadIdx.x; i < NTOK/HB; i += 256) atomicAdd(&h[seg[base+i]], 1);
  __syncthreads();
  for (int i = threadIdx.x; i < NSEG; i += 256){
    int c = h[i];
    if (c) h[i] = atomicAdd(&cur[i], c);     // reserve contiguous range; h becomes cursor
  }
  __syncthreads();
  for (int i = threadIdx.x; i < NTOK/HB; i += 256){
    int sg = seg[base+i];
    int p = atomicAdd(&h[sg], 1);
    sorted[p] = base+i;
  }
}

// ---------------- K4: segmented reduce over sorted tokens -> pooled [1024][768] bf16 ----------------
template<int USEB>
__global__ __launch_bounds__(256) void k4_pool(const float* __restrict__ feats, const short* __restrict__ featsb,
    const int* __restrict__ sorted, const int* __restrict__ segstart,
    const float* __restrict__ logits, const unsigned* __restrict__ bmax, const float* __restrict__ bz,
    short* __restrict__ pooledb){
  __shared__ float redS[4][DIM];
  __shared__ float redM[4][DIM];
  __shared__ float redA[4][DIM];
  __shared__ int   ltok[K4CH];
  __shared__ float lwgt[K4CH];
  int sgi = blockIdx.x;
  int b = sgi >> 6;
  int s = segstart[sgi], e = segstart[sgi+1];
  int cnt = e - s;
  float m = fdecode(bmax[b]);
  float invz = 1.0f / bz[b];
  int lane = threadIdx.x & 63, grp = threadIdx.x >> 6;
  float4 sum = make_float4(0.f,0.f,0.f,0.f), att = make_float4(0.f,0.f,0.f,0.f);
  float4 mx  = make_float4(-INFINITY,-INFINITY,-INFINITY,-INFINITY);
  for (int c0 = s; c0 < e; c0 += K4CH){
    int csz = min(K4CH, e - c0);
    for (int j = threadIdx.x; j < csz; j += 256){
      int t = sorted[c0 + j];
      ltok[j] = t;
      lwgt[j] = expf(logits[t] - m) * invz;
    }
    __syncthreads();
    for (int j = grp; j < csz; j += 4){
      int tok = ltok[j];
      float w = lwgt[j];
      float4 x;
      if (USEB){
        short4 h = *(const short4*)(featsb + (size_t)tok*DIM + lane*4);
        x = make_float4(bf2f(h.x), bf2f(h.y), bf2f(h.z), bf2f(h.w));
      } else {
        x = *(const float4*)(feats + (size_t)tok*DIM + lane*4);
      }
      sum.x += x.x; sum.y += x.y; sum.z += x.z; sum.w += x.w;
      mx.x = fmaxf(mx.x, x.x); mx.y = fmaxf(mx.y, x.y);
      mx.z = fmaxf(mx.z, x.z); mx.w = fmaxf(mx.w, x.w);
      att.x += x.x*w; att.y += x.y*w; att.z += x.z*w; att.w += x.w*w;
    }
    __syncthreads();
  }
  *(float4*)&redS[grp][lane*4] = sum;
  *(float4*)&redM[grp][lane*4] = mx;
  *(float4*)&redA[grp][lane*4] = att;
  __syncthreads();
  int d = threadIdx.x;
  float rs = redS[0][d] + redS[1][d] + redS[2][d] + redS[3][d];
  float rm = fmaxf(fmaxf(redM[0][d], redM[1][d]), fmaxf(redM[2][d], redM[3][d]));
  float ra = redA[0][d] + redA[1][d] + redA[2][d] + redA[3][d];
  float inv = 1.0f / (float)(cnt > 1 ? cnt : 1);
  size_t rb_ = (size_t)sgi * K3D;
  pooledb[rb_ + d]         = f2bf(rs * inv);
  pooledb[rb_ + DIM + d]   = f2bf(cnt > 0 ? rm : 0.f);
  pooledb[rb_ + 2*DIM + d] = f2bf(ra);
}

// ---------------- small MFMA GEMM: C[M,N] = act(A[M,K] @ Bt[N,K]^T + bias) -> bf16 ----------------
template<int GELU>
__global__ __launch_bounds__(256) void gemm64(const short* __restrict__ A, const short* __restrict__ Bt,
    const float* __restrict__ bias, short* __restrict__ Cout, int K, int ldc){
  __shared__ short lA[64][40];
  __shared__ short lB[64][40];
  int tid = threadIdx.x;
  int wave = tid >> 6, lane = tid & 63;
  int wm = wave >> 1, wn = wave & 1;
  int rb = blockIdx.x * 64, cb = blockIdx.y * 64;
  int l15 = lane & 15, lg = lane >> 4;
  f32x4 acc[2][2] = {};
  int srow = tid >> 2, skg = tid & 3;
  for (int ks = 0; ks < K; ks += 32){
    __syncthreads();
    *(short8*)&lA[srow][skg*8] = *(const short8*)(A  + (size_t)(rb+srow)*K + ks + skg*8);
    *(short8*)&lB[srow][skg*8] = *(const short8*)(Bt + (size_t)(cb+srow)*K + ks + skg*8);
    __syncthreads();
    short8 af[2], bf[2];
#pragma unroll
    for (int f = 0; f < 2; ++f){
      af[f] = *(const short8*)&lA[wm*32 + f*16 + l15][lg*8];
      bf[f] = *(const short8*)&lB[wn*32 + f*16 + l15][lg*8];
    }
#pragma unroll
    for (int fm = 0; fm < 2; ++fm)
#pragma unroll
      for (int fn = 0; fn < 2; ++fn)
        acc[fm][fn] = __builtin_amdgcn_mfma_f32_16x16x32_bf16(af[fm], bf[fn], acc[fm][fn], 0, 0, 0);
  }
#pragma unroll
  for (int fm = 0; fm < 2; ++fm)
#pragma unroll
    for (int fn = 0; fn < 2; ++fn){
      int col = cb + wn*32 + fn*16 + l15;
      float bcv = bias[col];
#pragma unroll
      for (int r = 0; r < 4; ++r){
        int row = rb + wm*32 + fm*16 + lg*4 + r;
        float v = acc[fm][fn][r] + bcv;
        if (GELU) v = 0.5f * v * (1.0f + erff(v * 0.70710678118f));
        Cout[(size_t)row*ldc + col] = f2bf(v);
      }
    }
}

// ---------------- K_lfp: lfp[1024][256] = lfb @ Wct[:, 0:256]^T + bc (f32 out) ----------------
__global__ __launch_bounds__(256) void k_lfp(const short* __restrict__ A, const short* __restrict__ Bt,
    const float* __restrict__ bias, float* __restrict__ Cout){
  __shared__ short lA[64][40];
  __shared__ short lB[64][40];
  int tid = threadIdx.x;
  int wave = tid >> 6, lane = tid & 63;
  int wm = wave >> 1, wn = wave & 1;
  int rb = blockIdx.x * 64, cb = blockIdx.y * 64;
  int l15 = lane & 15, lg = lane >> 4;
  f32x4 acc[2][2] = {};
  int srow = tid >> 2, skg = tid & 3;
  for (int ks = 0; ks < 256; ks += 32){
    __syncthreads();
    *(short8*)&lA[srow][skg*8] = *(const short8*)(A  + (size_t)(rb+srow)*DIM + ks + skg*8);
    *(short8*)&lB[srow][skg*8] = *(const short8*)(Bt + (size_t)(cb+srow)*K2D + ks + skg*8);
    __syncthreads();
    short8 af[2], bf[2];
#pragma unroll
    for (int f = 0; f < 2; ++f){
      af[f] = *(const short8*)&lA[wm*32 + f*16 + l15][lg*8];
      bf[f] = *(const short8*)&lB[wn*32 + f*16 + l15][lg*8];
    }
#pragma unroll
    for (int fm = 0; fm < 2; ++fm)
#pragma unroll
      for (int fn = 0; fn < 2; ++fn)
        acc[fm][fn] = __builtin_amdgcn_mfma_f32_16x16x32_bf16(af[fm], bf[fn], acc[fm][fn], 0, 0, 0);
  }
#pragma unroll
  for (int fm = 0; fm < 2; ++fm)
#pragma unroll
    for (int fn = 0; fn < 2; ++fn){
      int col = cb + wn*32 + fn*16 + l15;
      float bcv = bias[col];
#pragma unroll
      for (int r = 0; r < 4; ++r){
        int row = rb + wm*32 + fm*16 + lg*4 + r;
        Cout[(size_t)row*DIM + col] = acc[fm][fn][r] + bcv;
      }
    }
}

// ---------------- K5 v4: out = featsb @ Wct[:,256:512]^T + gather(lfp, seg) ----------------
// K=256 (lf-half precomputed into lfp). Block tile 128x128, 8 waves (2Mx4N),
// wave tile 64x32 -> acc[4][2]. Double-buffered, depth-2 prefetch, 1 barrier/K-step.
// out stores nontemporal (write-once, never reread; keeps L2 for featsb/lfp/Wct).
template<int USEB>
__global__ __launch_bounds__(512, 4) void k5_final(const float* __restrict__ feats,
    const short* __restrict__ featsb, const float* __restrict__ lfp,
    const int* __restrict__ seg, const short* __restrict__ Wct,
    float* __restrict__ out){
  __shared__ short lA[2][128][72];
  __shared__ short lB[2][128][72];
  int tid = threadIdx.x;
  int wave = tid >> 6, lane = tid & 63;
  int wm = wave >> 2, wn = wave & 3;
  int bid = (int)blockIdx.x;
  int swz = (bid & 7) * 256 + (bid >> 3);     // XCD-aware, bijective (2048 % 8 == 0)
  int rb = (swz >> 1) * 128;                  // adjacent swz share the A row-panel
  int cb = (swz & 1) * 128;
  int l15 = lane & 15, lg = lane >> 4;
  int arow0 = tid >> 3, arow1 = (tid >> 3) + 64, akg = tid & 7;
  const short* fbp0  = featsb + (size_t)(rb + arow0)*DIM + akg*8;
  const short* fbp1  = featsb + (size_t)(rb + arow1)*DIM + akg*8;
  const float* ffp0  = feats  + (size_t)(rb + arow0)*DIM + akg*8;
  const float* ffp1  = feats  + (size_t)(rb + arow1)*DIM + akg*8;
  const short* wp0 = Wct + (size_t)(cb + arow0)*K2D + 256 + akg*8;   // feats half of Wc
  const short* wp1 = Wct + (size_t)(cb + arow1)*K2D + 256 + akg*8;
  short8 ra0, ra1, rb0, rb1; f32x4 fa00, fa01, fa10, fa11;
  auto LOAD = [&](int t){
    if (USEB){
      ra0 = *(const short8*)(fbp0 + t*64);
      ra1 = *(const short8*)(fbp1 + t*64);
    } else {
      const f32x4* p0 = (const f32x4*)(ffp0 + (size_t)t*64); fa00 = p0[0]; fa01 = p0[1];
      const f32x4* p1 = (const f32x4*)(ffp1 + (size_t)t*64); fa10 = p1[0]; fa11 = p1[1];
    }
    rb0 = *(const short8*)(wp0 + t*64);
    rb1 = *(const short8*)(wp1 + t*64);
  };
  auto WRITE = [&](int t){
    int buf = t & 1;
    if (!USEB){
      short8 v;
      v[0]=f2bf(fa00[0]); v[1]=f2bf(fa00[1]); v[2]=f2bf(fa00[2]); v[3]=f2bf(fa00[3]);
      v[4]=f2bf(fa01[0]); v[5]=f2bf(fa01[1]); v[6]=f2bf(fa01[2]); v[7]=f2bf(fa01[3]);
      *(short8*)&lA[buf][arow0][akg*8] = v;
      v[0]=f2bf(fa10[0]); v[1]=f2bf(fa10[1]); v[2]=f2bf(fa10[2]); v[3]=f2bf(fa10[3]);
      v[4]=f2bf(fa11[0]); v[5]=f2bf(fa11[1]); v[6]=f2bf(fa11[2]); v[7]=f2bf(fa11[3]);
      *(short8*)&lA[buf][arow1][akg*8] = v;
    } else {
      *(short8*)&lA[buf][arow0][akg*8] = ra0;
      *(short8*)&lA[buf][arow1][akg*8] = ra1;
    }
    *(short8*)&lB[buf][arow0][akg*8] = rb0;
    *(short8*)&lB[buf][arow1][akg*8] = rb1;
  };
  f32x4 acc[4][2] = {};
  LOAD(0); WRITE(0); LOAD(1);
  __syncthreads();
  for (int ks = 0; ks < 4; ++ks){
    int cur = ks & 1;
    if (ks < 3) WRITE(ks+1);
    if (ks < 2) LOAD(ks+2);
#pragma unroll
    for (int kk = 0; kk < 2; ++kk){
      short8 af[4], bf[2];
#pragma unroll
      for (int f = 0; f < 4; ++f)
        af[f] = *(const short8*)&lA[cur][wm*64 + f*16 + l15][kk*32 + lg*8];
#pragma unroll
      for (int f = 0; f < 2; ++f)
        bf[f] = *(const short8*)&lB[cur][wn*32 + f*16 + l15][kk*32 + lg*8];
#pragma unroll
      for (int fm = 0; fm < 4; ++fm)
#pragma unroll
        for (int fn = 0; fn < 2; ++fn)
          acc[fm][fn] = __builtin_amdgcn_mfma_f32_16x16x32_bf16(af[fm], bf[fn], acc[fm][fn], 0, 0, 0);
    }
    __syncthreads();
  }
#pragma unroll
  for (int fm = 0; fm < 4; ++fm){
    int rbase = rb + wm*64 + fm*16 + lg*4;
    int4 sg4 = *(const int4*)(seg + rbase);
    int sgs[4] = {sg4.x, sg4.y, sg4.z, sg4.w};
#pragma unroll
    for (int fn = 0; fn < 2; ++fn){
      int col = cb + wn*32 + fn*16 + l15;
#pragma unroll
      for (int r = 0; r < 4; ++r){
        float v = acc[fm][fn][r] + lfp[(size_t)sgs[r]*DIM + col];
        __builtin_nontemporal_store(v, &out[(size_t)(rbase+r)*DIM + col]);
      }
    }
  }
}

extern "C" void kernel_launch(void* const* d_in, const int* in_sizes, int n_in,
                              void* d_out, int out_size, void* d_ws, size_t ws_size,
                              hipStream_t stream){
  const float* feats     = (const float*)d_in[0];
  const int*   cu        = (const int*)d_in[1];
  const int*   layer_ids = (const int*)d_in[2];
  const float* Wa        = (const float*)d_in[3];
  const float* ba        = (const float*)d_in[4];
  const float* W1        = (const float*)d_in[5];
  const float* b1        = (const float*)d_in[6];
  const float* W2        = (const float*)d_in[7];
  const float* b2        = (const float*)d_in[8];
  const float* Wc        = (const float*)d_in[9];
  const float* bc        = (const float*)d_in[10];
  float* out = (float*)d_out;

  char* w = (char*)d_ws;
  auto alloc = [&](size_t bytes)->char*{ char* p = w; w += (bytes + 255) & ~255ull; return p; };
  float*    logits  = (float*)   alloc((size_t)NTOK*4);
  int*      seg     = (int*)     alloc((size_t)NTOK*4);
  int*      sorted  = (int*)     alloc((size_t)NTOK*4);
  int*      segcnt  = (int*)     alloc((size_t)NSEG*4);
  int*      segstart= (int*)     alloc((size_t)(NSEG+1)*4);
  int*      cur     = (int*)     alloc((size_t)NSEG*4);
  unsigned* bmax    = (unsigned*)alloc(NB*4);
  float*    bz      = (float*)   alloc(NB*4);
  short*    W1t     = (short*)   alloc((size_t)512*768*2);
  short*    W2t     = (short*)   alloc((size_t)256*512*2);
  short*    Wct     = (short*)   alloc((size_t)256*512*2);
  short*    pooledb = (short*)   alloc((size_t)NSEG*K3D*2);
  short*    hb      = (short*)   alloc((size_t)NSEG*EDIM*2);
  short*    lfb     = (short*)   alloc((size_t)NSEG*DIM*2);
  float*    lfp     = (float*)   alloc((size_t)NSEG*DIM*4);
  short*    featsb  = (short*)   alloc((size_t)NTOK*DIM*2);     // 67 MB, gated
  size_t need = (size_t)(w - (char*)d_ws);
  bool useb = (ws_size >= need);

  k0_transpose<<<dim3(160), dim3(256), 0, stream>>>(W1, W2, Wc, W1t, W2t, Wct, bmax, segcnt);
  if (useb)
    k1_logits<1><<<dim3(2048), dim3(256), 0, stream>>>(feats, cu, layer_ids, Wa, ba, logits, seg, bmax, featsb, segcnt);
  else
    k1_logits<0><<<dim3(2048), dim3(256), 0, stream>>>(feats, cu, layer_ids, Wa, ba, logits, seg, bmax, featsb, segcnt);
  k2_z<<<dim3(NB), dim3(256), 0, stream>>>(logits, cu, bmax, bz);
  k3b_scan<<<dim3(1), dim3(1024), 0, stream>>>(segcnt, segstart, cur);
  k3c_scatter<<<dim3(HB), dim3(256), 0, stream>>>(seg, cur, sorted);
  if (useb)
    k4_pool<1><<<dim3(NSEG), dim3(256), 0, stream>>>(feats, featsb, sorted, segstart, logits, bmax, bz, pooledb);
  else
    k4_pool<0><<<dim3(NSEG), dim3(256), 0, stream>>>(feats, featsb, sorted, segstart, logits, bmax, bz, pooledb);
  gemm64<1><<<dim3(16, 8), dim3(256), 0, stream>>>(pooledb, W1t, b1, hb, 768, 512);
  gemm64<0><<<dim3(16, 4), dim3(256), 0, stream>>>(hb, W2t, b2, lfb, 512, 256);
  k_lfp<<<dim3(16, 4), dim3(256), 0, stream>>>(lfb, Wct, bc, lfp);
  if (useb)
    k5_final<1><<<dim3(2048), dim3(512), 0, stream>>>(feats, featsb, lfp, seg, Wct, out);
  else
    k5_final<0><<<dim3(2048), dim3(512), 0, stream>>>(feats, featsb, lfp, seg, Wct, out);
}

// Round 15
// 154.440 us; speedup vs baseline: 1.1412x; 1.0435x over previous
//
#include <hip/hip_runtime.h>
#include <hip/hip_bf16.h>
#include <math.h>

#define NTOK 131072
#define DIM  256
#define EDIM 512
#define NB   16
#define NL   64
#define NSEG (NB*NL)    // 1024
#define K3D  768        // 3*DIM
#define K2D  512        // 2*DIM
#define HB   64         // histogram/scatter blocks (2048 tokens each)
#define K4CH 256        // k4 LDS staging chunk (tokens)

typedef __attribute__((ext_vector_type(8))) short short8;
typedef __attribute__((ext_vector_type(4))) float f32x4;

// monotone float<->uint code so atomicMax(uint) == float max
static __device__ __forceinline__ unsigned fcode(float x){
  unsigned b = __float_as_uint(x);
  return (b & 0x80000000u) ? ~b : (b | 0x80000000u);
}
static __device__ __forceinline__ float fdecode(unsigned c){
  unsigned b = (c & 0x80000000u) ? (c ^ 0x80000000u) : ~c;
  return __uint_as_float(b);
}
#define NEG_INF_CODE 0x007FFFFFu   // fcode(-inf)

static __device__ __forceinline__ short f2bf(float x){
  union { __hip_bfloat16 h; short s; } u; u.h = __float2bfloat16(x); return u.s;
}
static __device__ __forceinline__ float bf2f(short s){
  union { float f; unsigned u; } u; u.u = ((unsigned)(unsigned short)s) << 16; return u.f;
}

// ---------------- K0t: transpose+convert weights to bf16 [N][K]; init bmax + segcnt ----------------
__global__ __launch_bounds__(256) void k0_transpose(const float* __restrict__ W1, const float* __restrict__ W2,
                                                    const float* __restrict__ Wc,
                                                    short* __restrict__ W1t, short* __restrict__ W2t,
                                                    short* __restrict__ Wct, unsigned* __restrict__ bmax,
                                                    int* __restrict__ segcnt){
  if (blockIdx.x == 0){
    if (threadIdx.x < NB) bmax[threadIdx.x] = NEG_INF_CODE;
    for (int i = threadIdx.x; i < NSEG; i += 256) segcnt[i] = 0;
  }
  __shared__ short tile[64][65];
  int b = blockIdx.x;
  const float* src; short* dst; int K, N, kt, nt;
  if (b < 96){ src=W1; dst=W1t; K=768; N=512; kt=b/8;  nt=b%8;  }
  else if (b < 128){ int c=b-96;  src=W2; dst=W2t; K=512; N=256; kt=c/4; nt=c%4; }
  else             { int c=b-128; src=Wc; dst=Wct; K=512; N=256; kt=c/4; nt=c%4; }
  int k0 = kt*64, n0 = nt*64;
  for (int e = threadIdx.x; e < 4096; e += 256){
    int r = e >> 6, c = e & 63;                       // r: k-row, c: n-col (coalesced read)
    tile[c][r] = f2bf(src[(size_t)(k0+r)*N + n0 + c]);
  }
  __syncthreads();
  for (int e = threadIdx.x; e < 4096; e += 256){
    int r = e >> 6, c = e & 63;                       // r: n-row, c: k-col (coalesced write)
    dst[(size_t)(n0+r)*K + k0 + c] = tile[r][c];
  }
}

// ---------------- K1 v5: logits + seg + per-batch max + bf16 emit ----------------
template<int WRITEB>
__global__ __launch_bounds__(256) void k1_logits(const float* __restrict__ feats, const int* __restrict__ cu,
    const int* __restrict__ layer_ids, const float* __restrict__ Wa, const float* __restrict__ ba,
    float* __restrict__ logits, int* __restrict__ seg, unsigned* __restrict__ bmax,
    short* __restrict__ featsb){
  __shared__ int      lcu[NB];
  __shared__ unsigned lbm[NB];
  int tid = threadIdx.x;
  if (tid < NB){ lcu[tid] = cu[tid+1]; lbm[tid] = NEG_INF_CODE; }
  int s = tid & 15;                      // lane within row
  int rowoff = tid >> 4;                 // 0..15
  float4 w0 = *(const float4*)(Wa + s*4);
  float4 w1 = *(const float4*)(Wa + 64 + s*4);
  float4 w2 = *(const float4*)(Wa + 128 + s*4);
  float4 w3 = *(const float4*)(Wa + 192 + s*4);
  float bav = ba[0];
  __syncthreads();
#pragma unroll
  for (int it = 0; it < 4; ++it){
    int r = (blockIdx.x + it*2048)*16 + rowoff;
    const float4* fp = (const float4*)(feats + (size_t)r*DIM);
    float4 x0 = fp[s], x1 = fp[16+s], x2 = fp[32+s], x3 = fp[48+s];
    float a = x0.x*w0.x + x0.y*w0.y + x0.z*w0.z + x0.w*w0.w
            + x1.x*w1.x + x1.y*w1.y + x1.z*w1.z + x1.w*w1.w
            + x2.x*w2.x + x2.y*w2.y + x2.z*w2.z + x2.w*w2.w
            + x3.x*w3.x + x3.y*w3.y + x3.z*w3.z + x3.w*w3.w;
    if (WRITEB){
      short4* ob = (short4*)(featsb + (size_t)r*DIM);
      short4 v;
      v.x=f2bf(x0.x); v.y=f2bf(x0.y); v.z=f2bf(x0.z); v.w=f2bf(x0.w); ob[s]    = v;
      v.x=f2bf(x1.x); v.y=f2bf(x1.y); v.z=f2bf(x1.z); v.w=f2bf(x1.w); ob[16+s] = v;
      v.x=f2bf(x2.x); v.y=f2bf(x2.y); v.z=f2bf(x2.z); v.w=f2bf(x2.w); ob[32+s] = v;
      v.x=f2bf(x3.x); v.y=f2bf(x3.y); v.z=f2bf(x3.z); v.w=f2bf(x3.w); ob[48+s] = v;
    }
    a += __shfl_xor(a, 1);
    a += __shfl_xor(a, 2);
    a += __shfl_xor(a, 4);
    a += __shfl_xor(a, 8);
    if (s == 0){
      float lg = a + bav;
      logits[r] = lg;
      int b = 0;
#pragma unroll
      for (int j = 0; j < NB-1; ++j) b += (lcu[j] <= r) ? 1 : 0;
      seg[r] = b*NL + layer_ids[r];
      atomicMax(&lbm[b], fcode(lg));
    }
  }
  __syncthreads();
  if (tid < NB && lbm[tid] != NEG_INF_CODE) atomicMax(&bmax[tid], lbm[tid]);
}

// ---------------- K23: fused {segment counts | batch-Z} ----------------
// blocks 0..HB-1: LDS hist -> global segcnt atomics (int, order-exact);
// blocks HB..HB+NB-1: per-batch softmax denominator.
__global__ __launch_bounds__(256) void k23_hist_z(const int* __restrict__ seg, int* __restrict__ segcnt,
    const float* __restrict__ logits, const int* __restrict__ cu,
    const unsigned* __restrict__ bmax, float* __restrict__ bz){
  __shared__ int h[NSEG];
  int bid = blockIdx.x;
  if (bid < HB){
    for (int i = threadIdx.x; i < NSEG; i += 256) h[i] = 0;
    __syncthreads();
    int base = bid * (NTOK/HB);
    for (int i = threadIdx.x; i < NTOK/HB; i += 256) atomicAdd(&h[seg[base+i]], 1);
    __syncthreads();
    for (int i = threadIdx.x; i < NSEG; i += 256){ int c = h[i]; if (c) atomicAdd(&segcnt[i], c); }
  } else {
    float* red = (float*)h;
    int b = bid - HB;
    int s = cu[b], e = cu[b+1];
    float m = fdecode(bmax[b]);
    float acc = 0.f;
    for (int i = s + threadIdx.x; i < e; i += 256)
      acc += expf(logits[i] - m);
    red[threadIdx.x] = acc; __syncthreads();
    for (int off = 128; off; off >>= 1){
      if (threadIdx.x < off) red[threadIdx.x] += red[threadIdx.x + off];
      __syncthreads();
    }
    if (threadIdx.x == 0) bz[b] = red[0];
  }
}

// ---------------- K3b: scan segcnt -> segstart + cur (single tiny block) ----------------
__global__ __launch_bounds__(1024) void k3b_scan(const int* __restrict__ segcnt, int* __restrict__ segstart,
                                                 int* __restrict__ cur){
  __shared__ int sc[NSEG];
  int s = threadIdx.x;
  int tot = segcnt[s];
  sc[s] = tot; __syncthreads();
  for (int off = 1; off < NSEG; off <<= 1){
    int v = (s >= off) ? sc[s-off] : 0;
    __syncthreads();
    sc[s] += v;
    __syncthreads();
  }
  int base = sc[s] - tot;   // exclusive prefix
  segstart[s] = base;
  cur[s] = base;
  if (s == 0) segstart[NSEG] = NTOK;
}

// ---------------- K3c: scatter via per-seg global range reservation ----------------
__global__ __launch_bounds__(256) void k3c_scatter(const int* __restrict__ seg, int* __restrict__ cur,
                                                   int* __restrict__ sorted){
  __shared__ int h[NSEG];
  for (int i = threadIdx.x; i < NSEG; i += 256) h[i] = 0;
  __syncthreads();
  int base = blockIdx.x * (NTOK/HB);
  for (int i = threadIdx.x; i < NTOK/HB; i += 256) atomicAdd(&h[seg[base+i]], 1);
  __syncthreads();
  for (int i = threadIdx.x; i < NSEG; i += 256){
    int c = h[i];
    if (c) h[i] = atomicAdd(&cur[i], c);     // reserve contiguous range; h becomes cursor
  }
  __syncthreads();
  for (int i = threadIdx.x; i < NTOK/HB; i += 256){
    int sg = seg[base+i];
    int p = atomicAdd(&h[sg], 1);
    sorted[p] = base+i;
  }
}

// ---------------- K4: segmented reduce over sorted tokens -> pooled [1024][768] bf16 ----------------
template<int USEB>
__global__ __launch_bounds__(256) void k4_pool(const float* __restrict__ feats, const short* __restrict__ featsb,
    const int* __restrict__ sorted, const int* __restrict__ segstart,
    const float* __restrict__ logits, const unsigned* __restrict__ bmax, const float* __restrict__ bz,
    short* __restrict__ pooledb){
  __shared__ float redS[4][DIM];
  __shared__ float redM[4][DIM];
  __shared__ float redA[4][DIM];
  __shared__ int   ltok[K4CH];
  __shared__ float lwgt[K4CH];
  int sgi = blockIdx.x;
  int b = sgi >> 6;
  int s = segstart[sgi], e = segstart[sgi+1];
  int cnt = e - s;
  float m = fdecode(bmax[b]);
  float invz = 1.0f / bz[b];
  int lane = threadIdx.x & 63, grp = threadIdx.x >> 6;
  float4 sum = make_float4(0.f,0.f,0.f,0.f), att = make_float4(0.f,0.f,0.f,0.f);
  float4 mx  = make_float4(-INFINITY,-INFINITY,-INFINITY,-INFINITY);
  for (int c0 = s; c0 < e; c0 += K4CH){
    int csz = min(K4CH, e - c0);
    for (int j = threadIdx.x; j < csz; j += 256){
      int t = sorted[c0 + j];
      ltok[j] = t;
      lwgt[j] = expf(logits[t] - m) * invz;
    }
    __syncthreads();
    for (int j = grp; j < csz; j += 4){
      int tok = ltok[j];
      float w = lwgt[j];
      float4 x;
      if (USEB){
        short4 h = *(const short4*)(featsb + (size_t)tok*DIM + lane*4);
        x = make_float4(bf2f(h.x), bf2f(h.y), bf2f(h.z), bf2f(h.w));
      } else {
        x = *(const float4*)(feats + (size_t)tok*DIM + lane*4);
      }
      sum.x += x.x; sum.y += x.y; sum.z += x.z; sum.w += x.w;
      mx.x = fmaxf(mx.x, x.x); mx.y = fmaxf(mx.y, x.y);
      mx.z = fmaxf(mx.z, x.z); mx.w = fmaxf(mx.w, x.w);
      att.x += x.x*w; att.y += x.y*w; att.z += x.z*w; att.w += x.w*w;
    }
    __syncthreads();
  }
  *(float4*)&redS[grp][lane*4] = sum;
  *(float4*)&redM[grp][lane*4] = mx;
  *(float4*)&redA[grp][lane*4] = att;
  __syncthreads();
  int d = threadIdx.x;
  float rs = redS[0][d] + redS[1][d] + redS[2][d] + redS[3][d];
  float rm = fmaxf(fmaxf(redM[0][d], redM[1][d]), fmaxf(redM[2][d], redM[3][d]));
  float ra = redA[0][d] + redA[1][d] + redA[2][d] + redA[3][d];
  float inv = 1.0f / (float)(cnt > 1 ? cnt : 1);
  size_t rb_ = (size_t)sgi * K3D;
  pooledb[rb_ + d]         = f2bf(rs * inv);
  pooledb[rb_ + DIM + d]   = f2bf(cnt > 0 ? rm : 0.f);
  pooledb[rb_ + 2*DIM + d] = f2bf(ra);
}

// ---------------- small MFMA GEMM: C[M,N] = act(A[M,K] @ Bt[N,K]^T + bias) -> bf16 ----------------
template<int GELU>
__global__ __launch_bounds__(256) void gemm64(const short* __restrict__ A, const short* __restrict__ Bt,
    const float* __restrict__ bias, short* __restrict__ Cout, int K, int ldc){
  __shared__ short lA[64][40];
  __shared__ short lB[64][40];
  int tid = threadIdx.x;
  int wave = tid >> 6, lane = tid & 63;
  int wm = wave >> 1, wn = wave & 1;
  int rb = blockIdx.x * 64, cb = blockIdx.y * 64;
  int l15 = lane & 15, lg = lane >> 4;
  f32x4 acc[2][2] = {};
  int srow = tid >> 2, skg = tid & 3;
  for (int ks = 0; ks < K; ks += 32){
    __syncthreads();
    *(short8*)&lA[srow][skg*8] = *(const short8*)(A  + (size_t)(rb+srow)*K + ks + skg*8);
    *(short8*)&lB[srow][skg*8] = *(const short8*)(Bt + (size_t)(cb+srow)*K + ks + skg*8);
    __syncthreads();
    short8 af[2], bf[2];
#pragma unroll
    for (int f = 0; f < 2; ++f){
      af[f] = *(const short8*)&lA[wm*32 + f*16 + l15][lg*8];
      bf[f] = *(const short8*)&lB[wn*32 + f*16 + l15][lg*8];
    }
#pragma unroll
    for (int fm = 0; fm < 2; ++fm)
#pragma unroll
      for (int fn = 0; fn < 2; ++fn)
        acc[fm][fn] = __builtin_amdgcn_mfma_f32_16x16x32_bf16(af[fm], bf[fn], acc[fm][fn], 0, 0, 0);
  }
#pragma unroll
  for (int fm = 0; fm < 2; ++fm)
#pragma unroll
    for (int fn = 0; fn < 2; ++fn){
      int col = cb + wn*32 + fn*16 + l15;
      float bcv = bias[col];
#pragma unroll
      for (int r = 0; r < 4; ++r){
        int row = rb + wm*32 + fm*16 + lg*4 + r;
        float v = acc[fm][fn][r] + bcv;
        if (GELU) v = 0.5f * v * (1.0f + erff(v * 0.70710678118f));
        Cout[(size_t)row*ldc + col] = f2bf(v);
      }
    }
}

// ---------------- K_lfp: lfp[1024][256] = lfb @ Wct[:, 0:256]^T + bc (f32 out) ----------------
__global__ __launch_bounds__(256) void k_lfp(const short* __restrict__ A, const short* __restrict__ Bt,
    const float* __restrict__ bias, float* __restrict__ Cout){
  __shared__ short lA[64][40];
  __shared__ short lB[64][40];
  int tid = threadIdx.x;
  int wave = tid >> 6, lane = tid & 63;
  int wm = wave >> 1, wn = wave & 1;
  int rb = blockIdx.x * 64, cb = blockIdx.y * 64;
  int l15 = lane & 15, lg = lane >> 4;
  f32x4 acc[2][2] = {};
  int srow = tid >> 2, skg = tid & 3;
  for (int ks = 0; ks < 256; ks += 32){
    __syncthreads();
    *(short8*)&lA[srow][skg*8] = *(const short8*)(A  + (size_t)(rb+srow)*DIM + ks + skg*8);
    *(short8*)&lB[srow][skg*8] = *(const short8*)(Bt + (size_t)(cb+srow)*K2D + ks + skg*8);
    __syncthreads();
    short8 af[2], bf[2];
#pragma unroll
    for (int f = 0; f < 2; ++f){
      af[f] = *(const short8*)&lA[wm*32 + f*16 + l15][lg*8];
      bf[f] = *(const short8*)&lB[wn*32 + f*16 + l15][lg*8];
    }
#pragma unroll
    for (int fm = 0; fm < 2; ++fm)
#pragma unroll
      for (int fn = 0; fn < 2; ++fn)
        acc[fm][fn] = __builtin_amdgcn_mfma_f32_16x16x32_bf16(af[fm], bf[fn], acc[fm][fn], 0, 0, 0);
  }
#pragma unroll
  for (int fm = 0; fm < 2; ++fm)
#pragma unroll
    for (int fn = 0; fn < 2; ++fn){
      int col = cb + wn*32 + fn*16 + l15;
      float bcv = bias[col];
#pragma unroll
      for (int r = 0; r < 4; ++r){
        int row = rb + wm*32 + fm*16 + lg*4 + r;
        Cout[(size_t)row*DIM + col] = acc[fm][fn][r] + bcv;
      }
    }
}

// ---------------- K5 v4: out = featsb @ Wct[:,256:512]^T + gather(lfp, seg) ----------------
// K=256 (lf-half precomputed into lfp). Block tile 128x128, 8 waves (2Mx4N),
// wave tile 64x32 -> acc[4][2]. Double-buffered, depth-2 prefetch, 1 barrier/K-step.
// Epilogue stores are nontemporal: out is write-once/never-reread -> keep L2 for featsb/lfp/Wct.
template<int USEB>
__global__ __launch_bounds__(512, 4) void k5_final(const float* __restrict__ feats,
    const short* __restrict__ featsb, const float* __restrict__ lfp,
    const int* __restrict__ seg, const short* __restrict__ Wct,
    float* __restrict__ out){
  __shared__ short lA[2][128][72];
  __shared__ short lB[2][128][72];
  int tid = threadIdx.x;
  int wave = tid >> 6, lane = tid & 63;
  int wm = wave >> 2, wn = wave & 3;
  int bid = (int)blockIdx.x;
  int swz = (bid & 7) * 256 + (bid >> 3);     // XCD-aware, bijective (2048 % 8 == 0)
  int rb = (swz >> 1) * 128;                  // adjacent swz share the A row-panel
  int cb = (swz & 1) * 128;
  int l15 = lane & 15, lg = lane >> 4;
  int arow0 = tid >> 3, arow1 = (tid >> 3) + 64, akg = tid & 7;
  const short* fbp0  = featsb + (size_t)(rb + arow0)*DIM + akg*8;
  const short* fbp1  = featsb + (size_t)(rb + arow1)*DIM + akg*8;
  const float* ffp0  = feats  + (size_t)(rb + arow0)*DIM + akg*8;
  const float* ffp1  = feats  + (size_t)(rb + arow1)*DIM + akg*8;
  const short* wp0 = Wct + (size_t)(cb + arow0)*K2D + 256 + akg*8;   // feats half of Wc
  const short* wp1 = Wct + (size_t)(cb + arow1)*K2D + 256 + akg*8;
  short8 ra0, ra1, rb0, rb1; float4 fa00, fa01, fa10, fa11;
  auto LOAD = [&](int t){
    if (USEB){
      ra0 = *(const short8*)(fbp0 + t*64);
      ra1 = *(const short8*)(fbp1 + t*64);
    } else {
      const float* p0 = ffp0 + (size_t)t*64; fa00 = *(const float4*)p0; fa01 = *(const float4*)(p0+4);
      const float* p1 = ffp1 + (size_t)t*64; fa10 = *(const float4*)p1; fa11 = *(const float4*)(p1+4);
    }
    rb0 = *(const short8*)(wp0 + t*64);
    rb1 = *(const short8*)(wp1 + t*64);
  };
  auto WRITE = [&](int t){
    int buf = t & 1;
    if (!USEB){
      short8 v;
      v[0]=f2bf(fa00.x); v[1]=f2bf(fa00.y); v[2]=f2bf(fa00.z); v[3]=f2bf(fa00.w);
      v[4]=f2bf(fa01.x); v[5]=f2bf(fa01.y); v[6]=f2bf(fa01.z); v[7]=f2bf(fa01.w);
      *(short8*)&lA[buf][arow0][akg*8] = v;
      v[0]=f2bf(fa10.x); v[1]=f2bf(fa10.y); v[2]=f2bf(fa10.z); v[3]=f2bf(fa10.w);
      v[4]=f2bf(fa11.x); v[5]=f2bf(fa11.y); v[6]=f2bf(fa11.z); v[7]=f2bf(fa11.w);
      *(short8*)&lA[buf][arow1][akg*8] = v;
    } else {
      *(short8*)&lA[buf][arow0][akg*8] = ra0;
      *(short8*)&lA[buf][arow1][akg*8] = ra1;
    }
    *(short8*)&lB[buf][arow0][akg*8] = rb0;
    *(short8*)&lB[buf][arow1][akg*8] = rb1;
  };
  f32x4 acc[4][2] = {};
  LOAD(0); WRITE(0); LOAD(1);
  __syncthreads();
  for (int ks = 0; ks < 4; ++ks){
    int cur = ks & 1;
    if (ks < 3) WRITE(ks+1);        // into buf[cur^1]; consumed at ks+1, barrier-protected
    if (ks < 2) LOAD(ks+2);         // issue early; lands under this phase's compute
#pragma unroll
    for (int kk = 0; kk < 2; ++kk){
      short8 af[4], bf[2];
#pragma unroll
      for (int f = 0; f < 4; ++f)
        af[f] = *(const short8*)&lA[cur][wm*64 + f*16 + l15][kk*32 + lg*8];
#pragma unroll
      for (int f = 0; f < 2; ++f)
        bf[f] = *(const short8*)&lB[cur][wn*32 + f*16 + l15][kk*32 + lg*8];
#pragma unroll
      for (int fm = 0; fm < 4; ++fm)
#pragma unroll
        for (int fn = 0; fn < 2; ++fn)
          acc[fm][fn] = __builtin_amdgcn_mfma_f32_16x16x32_bf16(af[fm], bf[fn], acc[fm][fn], 0, 0, 0);
    }
    __syncthreads();
  }
#pragma unroll
  for (int fm = 0; fm < 4; ++fm){
    int rbase = rb + wm*64 + fm*16 + lg*4;
    int4 sg4 = *(const int4*)(seg + rbase);
    int sgs[4] = {sg4.x, sg4.y, sg4.z, sg4.w};
#pragma unroll
    for (int fn = 0; fn < 2; ++fn){
      int col = cb + wn*32 + fn*16 + l15;
#pragma unroll
      for (int r = 0; r < 4; ++r){
        float v = acc[fm][fn][r] + lfp[(size_t)sgs[r]*DIM + col];
        __builtin_nontemporal_store(v, &out[(size_t)(rbase+r)*DIM + col]);
      }
    }
  }
}

extern "C" void kernel_launch(void* const* d_in, const int* in_sizes, int n_in,
                              void* d_out, int out_size, void* d_ws, size_t ws_size,
                              hipStream_t stream){
  const float* feats     = (const float*)d_in[0];
  const int*   cu        = (const int*)d_in[1];
  const int*   layer_ids = (const int*)d_in[2];
  const float* Wa        = (const float*)d_in[3];
  const float* ba        = (const float*)d_in[4];
  const float* W1        = (const float*)d_in[5];
  const float* b1        = (const float*)d_in[6];
  const float* W2        = (const float*)d_in[7];
  const float* b2        = (const float*)d_in[8];
  const float* Wc        = (const float*)d_in[9];
  const float* bc        = (const float*)d_in[10];
  float* out = (float*)d_out;

  char* w = (char*)d_ws;
  auto alloc = [&](size_t bytes)->char*{ char* p = w; w += (bytes + 255) & ~255ull; return p; };
  float*    logits  = (float*)   alloc((size_t)NTOK*4);
  int*      seg     = (int*)     alloc((size_t)NTOK*4);
  int*      sorted  = (int*)     alloc((size_t)NTOK*4);
  int*      segcnt  = (int*)     alloc((size_t)NSEG*4);
  int*      segstart= (int*)     alloc((size_t)(NSEG+1)*4);
  int*      cur     = (int*)     alloc((size_t)NSEG*4);
  unsigned* bmax    = (unsigned*)alloc(NB*4);
  float*    bz      = (float*)   alloc(NB*4);
  short*    W1t     = (short*)   alloc((size_t)512*768*2);
  short*    W2t     = (short*)   alloc((size_t)256*512*2);
  short*    Wct     = (short*)   alloc((size_t)256*512*2);
  short*    pooledb = (short*)   alloc((size_t)NSEG*K3D*2);
  short*    hb      = (short*)   alloc((size_t)NSEG*EDIM*2);
  short*    lfb     = (short*)   alloc((size_t)NSEG*DIM*2);
  float*    lfp     = (float*)   alloc((size_t)NSEG*DIM*4);
  short*    featsb  = (short*)   alloc((size_t)NTOK*DIM*2);     // 67 MB, gated
  size_t need = (size_t)(w - (char*)d_ws);
  bool useb = (ws_size >= need);

  k0_transpose<<<dim3(160), dim3(256), 0, stream>>>(W1, W2, Wc, W1t, W2t, Wct, bmax, segcnt);
  if (useb)
    k1_logits<1><<<dim3(2048), dim3(256), 0, stream>>>(feats, cu, layer_ids, Wa, ba, logits, seg, bmax, featsb);
  else
    k1_logits<0><<<dim3(2048), dim3(256), 0, stream>>>(feats, cu, layer_ids, Wa, ba, logits, seg, bmax, featsb);
  k23_hist_z<<<dim3(HB + NB), dim3(256), 0, stream>>>(seg, segcnt, logits, cu, bmax, bz);
  k3b_scan<<<dim3(1), dim3(1024), 0, stream>>>(segcnt, segstart, cur);
  k3c_scatter<<<dim3(HB), dim3(256), 0, stream>>>(seg, cur, sorted);
  if (useb)
    k4_pool<1><<<dim3(NSEG), dim3(256), 0, stream>>>(feats, featsb, sorted, segstart, logits, bmax, bz, pooledb);
  else
    k4_pool<0><<<dim3(NSEG), dim3(256), 0, stream>>>(feats, featsb, sorted, segstart, logits, bmax, bz, pooledb);
  gemm64<1><<<dim3(16, 8), dim3(256), 0, stream>>>(pooledb, W1t, b1, hb, 768, 512);
  gemm64<0><<<dim3(16, 4), dim3(256), 0, stream>>>(hb, W2t, b2, lfb, 512, 256);
  k_lfp<<<dim3(16, 4), dim3(256), 0, stream>>>(lfb, Wct, bc, lfp);
  if (useb)
    k5_final<1><<<dim3(2048), dim3(512), 0, stream>>>(feats, featsb, lfp, seg, Wct, out);
  else
    k5_final<0><<<dim3(2048), dim3(512), 0, stream>>>(feats, featsb, lfp, seg, Wct, out);
}